// Round 3
// baseline (152.974 us; speedup 1.0000x reference)
//
#include <hip/hip_runtime.h>
#include <stdint.h>

// MultiheadHollowAttention: hollow mask => attn == identity =>
//   out = (V@Wv^T + bv)@Wo^T + bo = V@(Wo@Wv)^T + (Wo@bv + bo)
// Precompute W = Wo@Wv (bf16 NT GEMM via WvT) and bias2 = Wo@bv+bo (fp32),
// then one NT bf16 MFMA GEMM: out = V@W^T + bias2.

typedef __attribute__((ext_vector_type(4))) float f32x4;
typedef __attribute__((ext_vector_type(8))) __bf16 bf16x8;
typedef __attribute__((ext_vector_type(4))) float float4v;
typedef __attribute__((ext_vector_type(8))) unsigned short ushort8;
typedef __attribute__((ext_vector_type(4))) unsigned short us4;

#define DEVINL __device__ __forceinline__

DEVINL unsigned short f2bf(float f) {
  union { float f; uint32_t u; } c; c.f = f;
  uint32_t r = c.u + 0x7FFFu + ((c.u >> 16) & 1u);  // RNE
  return (unsigned short)(r >> 16);
}

// async global->LDS, 16B per lane (HW: wave-uniform LDS base + lane*16)
#define GLD16(g, l) __builtin_amdgcn_global_load_lds( \
    (__attribute__((address_space(1))) void*)(g),     \
    (__attribute__((address_space(3))) void*)(l), 16, 0, 0)

// ---- fp32 -> bf16 convert for value (4096x1024) and Wo (1024x1024)
__global__ __launch_bounds__(256) void convert_v_wo(
    const float* __restrict__ V, const float* __restrict__ Wo,
    unsigned short* __restrict__ Vb, unsigned short* __restrict__ Wob) {
  const long NV = 4194304;
  long idx = ((long)blockIdx.x * 256 + threadIdx.x) * 8;
  const float* src; unsigned short* dst; long off;
  if (idx < NV) { src = V; dst = Vb; off = idx; }
  else          { src = Wo; dst = Wob; off = idx - NV; }
  float4v a = *(const float4v*)(src + off);
  float4v b = *(const float4v*)(src + off + 4);
  ushort8 o;
  o[0]=f2bf(a[0]); o[1]=f2bf(a[1]); o[2]=f2bf(a[2]); o[3]=f2bf(a[3]);
  o[4]=f2bf(b[0]); o[5]=f2bf(b[1]); o[6]=f2bf(b[2]); o[7]=f2bf(b[3]);
  *(ushort8*)(dst + off) = o;
}

// ---- Wv fp32 [1024][1024] -> WvT bf16 [1024][1024] (WvT[c][j] = Wv[j][c])
__global__ __launch_bounds__(256) void transp_wv(
    const float* __restrict__ Wv, unsigned short* __restrict__ WvT) {
  __shared__ unsigned short tile[64][65];
  const int c0 = (blockIdx.x & 15) * 64;   // col tile of Wv
  const int j0 = (blockIdx.x >> 4) * 64;   // row tile of Wv
  const int t = threadIdx.x;
  const int tr = t >> 4;
  const int tc = (t & 15) * 4;
  #pragma unroll
  for (int rr = 0; rr < 4; ++rr) {
    int row = tr + rr * 16;
    float4v v = *(const float4v*)(Wv + (long)(j0 + row) * 1024 + c0 + tc);
    tile[row][tc+0] = f2bf(v[0]);
    tile[row][tc+1] = f2bf(v[1]);
    tile[row][tc+2] = f2bf(v[2]);
    tile[row][tc+3] = f2bf(v[3]);
  }
  __syncthreads();
  #pragma unroll
  for (int rr = 0; rr < 4; ++rr) {
    int crow = tr + rr * 16;  // output row within tile = original col
    us4 o;
    #pragma unroll
    for (int i = 0; i < 4; ++i) o[i] = tile[tc + i][crow];
    *(us4*)(WvT + (long)(c0 + crow) * 1024 + j0 + tc) = o;
  }
}

// ---- bias2[n] = sum_j Wo[n][j]*bv[j] + bo[n]  (fp32)
__global__ __launch_bounds__(256) void bias2_kernel(
    const float* __restrict__ Wo, const float* __restrict__ bv,
    const float* __restrict__ bo, float* __restrict__ bias2) {
  const int w = threadIdx.x >> 6, lane = threadIdx.x & 63;
  const int row = blockIdx.x * 4 + w;
  float s = 0.f;
  #pragma unroll
  for (int c = 0; c < 4; ++c) {
    int col = c * 256 + lane * 4;
    float4v a = *(const float4v*)(Wo + (long)row * 1024 + col);
    float4v b = *(const float4v*)(bv + col);
    s += a[0]*b[0] + a[1]*b[1] + a[2]*b[2] + a[3]*b[3];
  }
  #pragma unroll
  for (int off = 32; off; off >>= 1) s += __shfl_down(s, off);
  if (lane == 0) bias2[row] = s + bo[row];
}

// ---- NT GEMM: C[m][n] = sum_k A[m][k]*B[n][k] (+ bias[n])
// N=K=1024 fixed. 128x128 tile, BK=64, 512 threads (8 waves: 2 row x 4 col,
// each wave owns 64x32). LDS XOR-swizzled (slot ^= row&7) via pre-swizzled
// global source so global_load_lds stays linear-dest.
template<int OUT_BF16, int ADD_BIAS>
__global__ __launch_bounds__(512) void gemm_nt(
    const unsigned short* __restrict__ A,
    const unsigned short* __restrict__ B,
    const float* __restrict__ bias,
    void* __restrict__ Cv) {
  constexpr int K = 1024, N = 1024;
  __shared__ alignas(16) unsigned short lA[128 * 64];
  __shared__ alignas(16) unsigned short lB[128 * 64];

  const int t = threadIdx.x;
  const int bm = blockIdx.x >> 3;      // row-tiles
  const int bn = blockIdx.x & 7;       // 8 col-tiles
  const int m0 = bm << 7, n0 = bn << 7;

  const int srow = t >> 3;             // 0..63
  const int swz = (t & 7) ^ (srow & 7);
  const unsigned short* gA0 = A + (long)(m0 + srow) * K + swz * 8;
  const unsigned short* gB0 = B + (long)(n0 + srow) * K + swz * 8;
  unsigned short* lA0 = lA + t * 8;
  unsigned short* lB0 = lB + t * 8;

  const int lane = t & 63;
  const int wr = t >> 8;               // wave row 0..1 (64 rows each)
  const int wc = (t >> 6) & 3;         // wave col 0..3 (32 cols each)
  const int fr = lane & 15;
  const int fq = lane >> 4;

  int aoff[4][2], boff[2][2];
  #pragma unroll
  for (int m = 0; m < 4; ++m) {
    int row = wr * 64 + m * 16 + fr;
    #pragma unroll
    for (int h = 0; h < 2; ++h)
      aoff[m][h] = row * 128 + (((h * 4 + fq) ^ (row & 7)) * 16);
  }
  #pragma unroll
  for (int n = 0; n < 2; ++n) {
    int row = wc * 32 + n * 16 + fr;
    #pragma unroll
    for (int h = 0; h < 2; ++h)
      boff[n][h] = row * 128 + (((h * 4 + fq) ^ (row & 7)) * 16);
  }

  f32x4 acc[4][2] = {};
  const char* lAb = (const char*)lA;
  const char* lBb = (const char*)lB;

  #pragma unroll 1
  for (int kt = 0; kt < K / 64; ++kt) {
    __syncthreads();
    const unsigned short* ga = gA0 + kt * 64;
    const unsigned short* gb = gB0 + kt * 64;
    GLD16(ga, lA0);
    GLD16(ga + 64 * K, lA0 + 4096);
    GLD16(gb, lB0);
    GLD16(gb + 64 * K, lB0 + 4096);
    __syncthreads();

    bf16x8 av[4][2], bw[2][2];
    #pragma unroll
    for (int m = 0; m < 4; ++m)
      #pragma unroll
      for (int h = 0; h < 2; ++h)
        av[m][h] = *(const bf16x8*)(lAb + aoff[m][h]);
    #pragma unroll
    for (int n = 0; n < 2; ++n)
      #pragma unroll
      for (int h = 0; h < 2; ++h)
        bw[n][h] = *(const bf16x8*)(lBb + boff[n][h]);

    #pragma unroll
    for (int m = 0; m < 4; ++m)
      #pragma unroll
      for (int n = 0; n < 2; ++n)
        #pragma unroll
        for (int h = 0; h < 2; ++h)
          acc[m][n] = __builtin_amdgcn_mfma_f32_16x16x32_bf16(
              av[m][h], bw[n][h], acc[m][n], 0, 0, 0);
  }

  // epilogue: D layout col=lane&15, row=(lane>>4)*4+j
  #pragma unroll
  for (int m = 0; m < 4; ++m) {
    #pragma unroll
    for (int n = 0; n < 2; ++n) {
      int gr = m0 + wr * 64 + m * 16 + fq * 4;
      int gc = n0 + wc * 32 + n * 16 + fr;
      float bb = 0.f;
      if (ADD_BIAS) bb = bias[gc];
      if (OUT_BF16) {
        unsigned short* C = (unsigned short*)Cv;
        #pragma unroll
        for (int j = 0; j < 4; ++j)
          C[(long)(gr + j) * N + gc] = f2bf(acc[m][n][j] + bb);
      } else {
        float* C = (float*)Cv;
        #pragma unroll
        for (int j = 0; j < 4; ++j)
          C[(long)(gr + j) * N + gc] = acc[m][n][j] + bb;
      }
    }
  }
}

extern "C" void kernel_launch(void* const* d_in, const int* in_sizes, int n_in,
                              void* d_out, int out_size, void* d_ws, size_t ws_size,
                              hipStream_t stream) {
  // dict order: 0:query 1:key 2:value 3:mask 4:Wq 5:bq 6:Wk 7:bk 8:Wv 9:bv 10:Wo 11:bo
  const float* value = (const float*)d_in[2];
  const float* Wv    = (const float*)d_in[8];
  const float* bv    = (const float*)d_in[9];
  const float* Wo    = (const float*)d_in[10];
  const float* bo    = (const float*)d_in[11];

  char* ws = (char*)d_ws;
  unsigned short* Vb    = (unsigned short*)(ws);              // 8 MiB
  unsigned short* Wob   = (unsigned short*)(ws + 8388608);    // 2 MiB
  unsigned short* WvTb  = (unsigned short*)(ws + 10485760);   // 2 MiB
  unsigned short* Wb    = (unsigned short*)(ws + 12582912);   // 2 MiB
  float*          bias2 = (float*)(ws + 14680064);            // 4 KiB
  float* out = (float*)d_out;

  convert_v_wo<<<2560, 256, 0, stream>>>(value, Wo, Vb, Wob);
  transp_wv<<<256, 256, 0, stream>>>(Wv, WvTb);
  bias2_kernel<<<256, 256, 0, stream>>>(Wo, bv, bo, bias2);
  gemm_nt<1, 0><<<64, 512, 0, stream>>>(Wob, WvTb, nullptr, Wb);  // W = Wo@Wv
  gemm_nt<0, 1><<<256, 512, 0, stream>>>(Vb, Wb, bias2, out);     // out = V@W^T + bias2
}

// Round 4
// 139.048 us; speedup vs baseline: 1.1001x; 1.1001x over previous
//
#include <hip/hip_runtime.h>
#include <stdint.h>

// MultiheadHollowAttention: hollow mask => attn == identity =>
//   out = V@(Wo@Wv)^T + (Wo@bv + bo)
// R4: fused prep kernel; W-GEMM at 64x64 tiles (256 blocks); main GEMM at
// 128x64 tiles (512 blocks, 2/CU) with 2-phase double-buffered prefetch.

typedef __attribute__((ext_vector_type(4))) float f32x4;
typedef __attribute__((ext_vector_type(8))) __bf16 bf16x8;
typedef __attribute__((ext_vector_type(4))) float float4v;
typedef __attribute__((ext_vector_type(8))) unsigned short ushort8;
typedef __attribute__((ext_vector_type(4))) unsigned short us4;

#define DEVINL __device__ __forceinline__

DEVINL unsigned short f2bf(float f) {
  union { float f; uint32_t u; } c; c.f = f;
  uint32_t r = c.u + 0x7FFFu + ((c.u >> 16) & 1u);  // RNE
  return (unsigned short)(r >> 16);
}

// async global->LDS, 16B per lane (HW: wave-uniform LDS base + lane*16)
#define GLD16(g, l) __builtin_amdgcn_global_load_lds( \
    (__attribute__((address_space(1))) void*)(g),     \
    (__attribute__((address_space(3))) void*)(l), 16, 0, 0)

// ---- fused prep: V->bf16 (2048 blk), Wo->bf16 (512), WvT bf16 (256), bias2 (256)
__global__ __launch_bounds__(256) void prep(
    const float* __restrict__ V, const float* __restrict__ Wv,
    const float* __restrict__ Wo, const float* __restrict__ bv,
    const float* __restrict__ bo,
    unsigned short* __restrict__ Vb, unsigned short* __restrict__ Wob,
    unsigned short* __restrict__ WvT, float* __restrict__ bias2) {
  __shared__ unsigned short tile[64][65];
  const int b = blockIdx.x, t = threadIdx.x;
  if (b < 2560) {                       // convert V (b<2048) or Wo
    const float* src = (b < 2048) ? V : Wo;
    unsigned short* dst = (b < 2048) ? Vb : Wob;
    long off = ((long)(b < 2048 ? b : b - 2048) * 256 + t) * 8;
    float4v a = *(const float4v*)(src + off);
    float4v c = *(const float4v*)(src + off + 4);
    ushort8 o;
    o[0]=f2bf(a[0]); o[1]=f2bf(a[1]); o[2]=f2bf(a[2]); o[3]=f2bf(a[3]);
    o[4]=f2bf(c[0]); o[5]=f2bf(c[1]); o[6]=f2bf(c[2]); o[7]=f2bf(c[3]);
    *(ushort8*)(dst + off) = o;
  } else if (b < 2816) {                // WvT[c][j] = bf16(Wv[j][c])
    const int tb = b - 2560;
    const int c0 = (tb & 15) * 64, j0 = (tb >> 4) * 64;
    const int tr = t >> 4, tc = (t & 15) * 4;
    #pragma unroll
    for (int rr = 0; rr < 4; ++rr) {
      int row = tr + rr * 16;
      float4v v = *(const float4v*)(Wv + (long)(j0 + row) * 1024 + c0 + tc);
      tile[row][tc+0] = f2bf(v[0]);
      tile[row][tc+1] = f2bf(v[1]);
      tile[row][tc+2] = f2bf(v[2]);
      tile[row][tc+3] = f2bf(v[3]);
    }
    __syncthreads();
    #pragma unroll
    for (int rr = 0; rr < 4; ++rr) {
      int crow = tr + rr * 16;
      us4 o;
      #pragma unroll
      for (int i = 0; i < 4; ++i) o[i] = tile[tc + i][crow];
      *(us4*)(WvT + (long)(c0 + crow) * 1024 + j0 + tc) = o;
    }
  } else {                              // bias2 = Wo@bv + bo
    const int tb = b - 2816;
    const int w = t >> 6, lane = t & 63;
    const int row = tb * 4 + w;
    float s = 0.f;
    #pragma unroll
    for (int c = 0; c < 4; ++c) {
      int col = c * 256 + lane * 4;
      float4v a = *(const float4v*)(Wo + (long)row * 1024 + col);
      float4v x = *(const float4v*)(bv + col);
      s += a[0]*x[0] + a[1]*x[1] + a[2]*x[2] + a[3]*x[3];
    }
    #pragma unroll
    for (int off = 32; off; off >>= 1) s += __shfl_down(s, off);
    if (lane == 0) bias2[row] = s + bo[row];
  }
}

// ---- NT GEMM: C[m][n] = sum_k A[m][k]*B[n][k] (+ bias[n]); N=K=1024.
// BMxBN tile, BK=64, NT threads as WMxWN waves (each wave SM=BM/WM x SN=BN/WN).
// Double-buffered LDS, 2-phase prefetch (stage next K-tile before compute,
// one barrier per iteration). XOR-swizzle (slot ^= row&7) via pre-swizzled
// global source (global_load_lds keeps linear dest) + swizzled ds_read.
template<int BM, int BN, int NT, int WM, int WN, int OUT_BF16, int ADD_BIAS>
__global__ __launch_bounds__(NT) void gemm_nt(
    const unsigned short* __restrict__ A,
    const unsigned short* __restrict__ B,
    const float* __restrict__ bias,
    void* __restrict__ Cv) {
  constexpr int K = 1024, N = 1024;
  constexpr int NBN = N / BN;
  constexpr int SM = BM / WM, SN = BN / WN;
  constexpr int FM = SM / 16, FN = SN / 16;
  constexpr int CA = BM * 8 / NT, CB = BN * 8 / NT;
  constexpr int NKT = K / 64;

  __shared__ alignas(16) unsigned short lA[2][BM * 64];
  __shared__ alignas(16) unsigned short lB[2][BN * 64];

  const int t = threadIdx.x;
  const int bm = blockIdx.x / NBN;
  const int bn = blockIdx.x % NBN;
  const int m0 = bm * BM, n0 = bn * BN;

  // staging descriptors (pre-swizzled global source, linear LDS dest)
  long gAoff[CA]; int lAoff[CA];
  #pragma unroll
  for (int c = 0; c < CA; ++c) {
    int s = c * NT + t, r = s >> 3, sl = (s & 7) ^ (r & 7);
    gAoff[c] = (long)(m0 + r) * K + sl * 8;
    lAoff[c] = s * 8;
  }
  long gBoff[CB]; int lBoff[CB];
  #pragma unroll
  for (int c = 0; c < CB; ++c) {
    int s = c * NT + t, r = s >> 3, sl = (s & 7) ^ (r & 7);
    gBoff[c] = (long)(n0 + r) * K + sl * 8;
    lBoff[c] = s * 8;
  }

  const int lane = t & 63;
  const int w = t >> 6, wm = w / WN, wn = w % WN;
  const int fr = lane & 15, fq = lane >> 4;

  int aoff[FM][2], boff[FN][2];
  #pragma unroll
  for (int m = 0; m < FM; ++m) {
    int row = wm * SM + m * 16 + fr;
    #pragma unroll
    for (int h = 0; h < 2; ++h)
      aoff[m][h] = row * 128 + (((h * 4 + fq) ^ (row & 7)) * 16);
  }
  #pragma unroll
  for (int n = 0; n < FN; ++n) {
    int row = wn * SN + n * 16 + fr;
    #pragma unroll
    for (int h = 0; h < 2; ++h)
      boff[n][h] = row * 128 + (((h * 4 + fq) ^ (row & 7)) * 16);
  }

  f32x4 acc[FM][FN] = {};

  // prologue: stage kt=0 into buffer 0
  #pragma unroll
  for (int c = 0; c < CA; ++c) GLD16(A + gAoff[c], (unsigned short*)lA[0] + lAoff[c]);
  #pragma unroll
  for (int c = 0; c < CB; ++c) GLD16(B + gBoff[c], (unsigned short*)lB[0] + lBoff[c]);
  __syncthreads();

  int cur = 0;
  #pragma unroll 1
  for (int kt = 0; kt < NKT; ++kt) {
    if (kt + 1 < NKT) {  // prefetch next K-tile into the other buffer
      #pragma unroll
      for (int c = 0; c < CA; ++c)
        GLD16(A + gAoff[c] + (kt + 1) * 64, (unsigned short*)lA[cur ^ 1] + lAoff[c]);
      #pragma unroll
      for (int c = 0; c < CB; ++c)
        GLD16(B + gBoff[c] + (kt + 1) * 64, (unsigned short*)lB[cur ^ 1] + lBoff[c]);
    }
    const char* lAb = (const char*)lA[cur];
    const char* lBb = (const char*)lB[cur];
    bf16x8 av[FM][2], bw[FN][2];
    #pragma unroll
    for (int m = 0; m < FM; ++m)
      #pragma unroll
      for (int h = 0; h < 2; ++h)
        av[m][h] = *(const bf16x8*)(lAb + aoff[m][h]);
    #pragma unroll
    for (int n = 0; n < FN; ++n)
      #pragma unroll
      for (int h = 0; h < 2; ++h)
        bw[n][h] = *(const bf16x8*)(lBb + boff[n][h]);

    #pragma unroll
    for (int m = 0; m < FM; ++m)
      #pragma unroll
      for (int n = 0; n < FN; ++n)
        #pragma unroll
        for (int h = 0; h < 2; ++h)
          acc[m][n] = __builtin_amdgcn_mfma_f32_16x16x32_bf16(
              av[m][h], bw[n][h], acc[m][n], 0, 0, 0);

    __syncthreads();   // prefetch landed (vmcnt drained) + compute done
    cur ^= 1;
  }

  // epilogue: D layout col=lane&15, row=(lane>>4)*4+j
  #pragma unroll
  for (int m = 0; m < FM; ++m) {
    #pragma unroll
    for (int n = 0; n < FN; ++n) {
      int gr = m0 + wm * SM + m * 16 + fq * 4;
      int gc = n0 + wn * SN + n * 16 + fr;
      float bb = 0.f;
      if (ADD_BIAS) bb = bias[gc];
      if (OUT_BF16) {
        unsigned short* C = (unsigned short*)Cv;
        #pragma unroll
        for (int j = 0; j < 4; ++j)
          C[(long)(gr + j) * N + gc] = f2bf(acc[m][n][j] + bb);
      } else {
        float* C = (float*)Cv;
        #pragma unroll
        for (int j = 0; j < 4; ++j)
          C[(long)(gr + j) * N + gc] = acc[m][n][j] + bb;
      }
    }
  }
}

extern "C" void kernel_launch(void* const* d_in, const int* in_sizes, int n_in,
                              void* d_out, int out_size, void* d_ws, size_t ws_size,
                              hipStream_t stream) {
  // dict order: 0:query 1:key 2:value 3:mask 4:Wq 5:bq 6:Wk 7:bk 8:Wv 9:bv 10:Wo 11:bo
  const float* value = (const float*)d_in[2];
  const float* Wv    = (const float*)d_in[8];
  const float* bv    = (const float*)d_in[9];
  const float* Wo    = (const float*)d_in[10];
  const float* bo    = (const float*)d_in[11];

  char* ws = (char*)d_ws;
  unsigned short* Vb    = (unsigned short*)(ws);              // 8 MiB
  unsigned short* Wob   = (unsigned short*)(ws + 8388608);    // 2 MiB
  unsigned short* WvTb  = (unsigned short*)(ws + 10485760);   // 2 MiB
  unsigned short* Wb    = (unsigned short*)(ws + 12582912);   // 2 MiB
  float*          bias2 = (float*)(ws + 14680064);            // 4 KiB
  float* out = (float*)d_out;

  prep<<<3072, 256, 0, stream>>>(value, Wv, Wo, bv, bo, Vb, Wob, WvTb, bias2);
  // W = Wo@Wv : 64x64 tiles -> 16x16 = 256 blocks
  gemm_nt<64, 64, 512, 2, 4, 1, 0><<<256, 512, 0, stream>>>(Wob, WvTb, nullptr, Wb);
  // out = V@W^T + bias2 : 128x64 tiles -> 32x16 = 512 blocks (2/CU)
  gemm_nt<128, 64, 512, 4, 2, 0, 1><<<512, 512, 0, stream>>>(Vb, Wb, bias2, out);
}

// Round 5
// 138.923 us; speedup vs baseline: 1.1011x; 1.0009x over previous
//
#include <hip/hip_runtime.h>
#include <stdint.h>

// MultiheadHollowAttention: hollow mask => attn == identity =>
//   out = V@(Wo@Wv)^T + (Wo@bv + bo)
// R5: prep_small (Wo cvt + WvT + bias2); fused {W-GEMM || V-convert} kernel;
// main GEMM 128x128 dbuf-prefetch with XCD-aware swizzle.

typedef __attribute__((ext_vector_type(4))) float f32x4;
typedef __attribute__((ext_vector_type(8))) __bf16 bf16x8;
typedef __attribute__((ext_vector_type(4))) float float4v;
typedef __attribute__((ext_vector_type(8))) unsigned short ushort8;
typedef __attribute__((ext_vector_type(4))) unsigned short us4;

#define DEVINL __device__ __forceinline__

DEVINL unsigned short f2bf(float f) {
  union { float f; uint32_t u; } c; c.f = f;
  uint32_t r = c.u + 0x7FFFu + ((c.u >> 16) & 1u);  // RNE
  return (unsigned short)(r >> 16);
}

// async global->LDS, 16B per lane (HW: wave-uniform LDS base + lane*16)
#define GLD16(g, l) __builtin_amdgcn_global_load_lds( \
    (__attribute__((address_space(1))) void*)(g),     \
    (__attribute__((address_space(3))) void*)(l), 16, 0, 0)

// ---- NT GEMM body: C[m][n] = sum_k A[m][k]*B[n][k] (+ bias[n]); N=K=1024.
// BMxBN tile, BK=64, NT threads as WMxWN waves. Double-buffered LDS, 2-phase
// prefetch, one barrier/iter (implicit vmcnt(0) drain at __syncthreads).
// XOR-swizzle (slot ^= row&7) via pre-swizzled global source + swizzled read.
template<int M, int BM, int BN, int NT, int WM, int WN, int OUT_BF16,
         int ADD_BIAS, int XCD>
DEVINL void gemm_body(int bidx, const unsigned short* __restrict__ A,
                      const unsigned short* __restrict__ B,
                      const float* __restrict__ bias, void* __restrict__ Cv) {
  constexpr int K = 1024, N = 1024;
  constexpr int NBN = N / BN;
  constexpr int NWG = (M / BM) * NBN;
  constexpr int SM = BM / WM, SN = BN / WN;
  constexpr int FM = SM / 16, FN = SN / 16;
  constexpr int CA = BM * 8 / NT, CB = BN * 8 / NT;
  constexpr int NKT = K / 64;

  __shared__ alignas(16) unsigned short lA[2][BM * 64];
  __shared__ alignas(16) unsigned short lB[2][BN * 64];

  const int t = threadIdx.x;
  int tile = bidx;
  if (XCD) {  // bijective (NWG%8==0): XCD x gets contiguous tile chunk
    tile = (bidx & 7) * (NWG / 8) + (bidx >> 3);
  }
  const int bm = tile / NBN;
  const int bn = tile % NBN;
  const int m0 = bm * BM, n0 = bn * BN;

  long gAoff[CA]; int lAoff[CA];
  #pragma unroll
  for (int c = 0; c < CA; ++c) {
    int s = c * NT + t, r = s >> 3, sl = (s & 7) ^ (r & 7);
    gAoff[c] = (long)(m0 + r) * K + sl * 8;
    lAoff[c] = s * 8;
  }
  long gBoff[CB]; int lBoff[CB];
  #pragma unroll
  for (int c = 0; c < CB; ++c) {
    int s = c * NT + t, r = s >> 3, sl = (s & 7) ^ (r & 7);
    gBoff[c] = (long)(n0 + r) * K + sl * 8;
    lBoff[c] = s * 8;
  }

  const int lane = t & 63;
  const int w = t >> 6, wm = w / WN, wn = w % WN;
  const int fr = lane & 15, fq = lane >> 4;

  int aoff[FM][2], boff[FN][2];
  #pragma unroll
  for (int m = 0; m < FM; ++m) {
    int row = wm * SM + m * 16 + fr;
    #pragma unroll
    for (int h = 0; h < 2; ++h)
      aoff[m][h] = row * 128 + (((h * 4 + fq) ^ (row & 7)) * 16);
  }
  #pragma unroll
  for (int n = 0; n < FN; ++n) {
    int row = wn * SN + n * 16 + fr;
    #pragma unroll
    for (int h = 0; h < 2; ++h)
      boff[n][h] = row * 128 + (((h * 4 + fq) ^ (row & 7)) * 16);
  }

  f32x4 acc[FM][FN] = {};

  #pragma unroll
  for (int c = 0; c < CA; ++c) GLD16(A + gAoff[c], (unsigned short*)lA[0] + lAoff[c]);
  #pragma unroll
  for (int c = 0; c < CB; ++c) GLD16(B + gBoff[c], (unsigned short*)lB[0] + lBoff[c]);
  __syncthreads();

  int cur = 0;
  #pragma unroll 1
  for (int kt = 0; kt < NKT; ++kt) {
    if (kt + 1 < NKT) {
      #pragma unroll
      for (int c = 0; c < CA; ++c)
        GLD16(A + gAoff[c] + (kt + 1) * 64, (unsigned short*)lA[cur ^ 1] + lAoff[c]);
      #pragma unroll
      for (int c = 0; c < CB; ++c)
        GLD16(B + gBoff[c] + (kt + 1) * 64, (unsigned short*)lB[cur ^ 1] + lBoff[c]);
    }
    const char* lAb = (const char*)lA[cur];
    const char* lBb = (const char*)lB[cur];
    bf16x8 av[FM][2], bw[FN][2];
    #pragma unroll
    for (int m = 0; m < FM; ++m)
      #pragma unroll
      for (int h = 0; h < 2; ++h)
        av[m][h] = *(const bf16x8*)(lAb + aoff[m][h]);
    #pragma unroll
    for (int n = 0; n < FN; ++n)
      #pragma unroll
      for (int h = 0; h < 2; ++h)
        bw[n][h] = *(const bf16x8*)(lBb + boff[n][h]);

    #pragma unroll
    for (int m = 0; m < FM; ++m)
      #pragma unroll
      for (int n = 0; n < FN; ++n)
        #pragma unroll
        for (int h = 0; h < 2; ++h)
          acc[m][n] = __builtin_amdgcn_mfma_f32_16x16x32_bf16(
              av[m][h], bw[n][h], acc[m][n], 0, 0, 0);

    __syncthreads();
    cur ^= 1;
  }

  // epilogue: D layout col=lane&15, row=(lane>>4)*4+j
  #pragma unroll
  for (int m = 0; m < FM; ++m) {
    #pragma unroll
    for (int n = 0; n < FN; ++n) {
      int gr = m0 + wm * SM + m * 16 + fq * 4;
      int gc = n0 + wn * SN + n * 16 + fr;
      float bb = 0.f;
      if (ADD_BIAS) bb = bias[gc];
      if (OUT_BF16) {
        unsigned short* C = (unsigned short*)Cv;
        #pragma unroll
        for (int j = 0; j < 4; ++j)
          C[(long)(gr + j) * N + gc] = f2bf(acc[m][n][j] + bb);
      } else {
        float* C = (float*)Cv;
        #pragma unroll
        for (int j = 0; j < 4; ++j)
          C[(long)(gr + j) * N + gc] = acc[m][n][j] + bb;
      }
    }
  }
}

// ---- prep_small: Wo->bf16 (512 blk), WvT bf16 (256 blk), bias2 (256 blk)
__global__ __launch_bounds__(256) void prep_small(
    const float* __restrict__ Wv, const float* __restrict__ Wo,
    const float* __restrict__ bv, const float* __restrict__ bo,
    unsigned short* __restrict__ Wob, unsigned short* __restrict__ WvT,
    float* __restrict__ bias2) {
  __shared__ unsigned short tile[64][65];
  const int b = blockIdx.x, t = threadIdx.x;
  if (b < 512) {                        // Wo -> bf16
    long off = ((long)b * 256 + t) * 8;
    float4v a = *(const float4v*)(Wo + off);
    float4v c = *(const float4v*)(Wo + off + 4);
    ushort8 o;
    o[0]=f2bf(a[0]); o[1]=f2bf(a[1]); o[2]=f2bf(a[2]); o[3]=f2bf(a[3]);
    o[4]=f2bf(c[0]); o[5]=f2bf(c[1]); o[6]=f2bf(c[2]); o[7]=f2bf(c[3]);
    *(ushort8*)(Wob + off) = o;
  } else if (b < 768) {                 // WvT[c][j] = bf16(Wv[j][c])
    const int tb = b - 512;
    const int c0 = (tb & 15) * 64, j0 = (tb >> 4) * 64;
    const int tr = t >> 4, tc = (t & 15) * 4;
    #pragma unroll
    for (int rr = 0; rr < 4; ++rr) {
      int row = tr + rr * 16;
      float4v v = *(const float4v*)(Wv + (long)(j0 + row) * 1024 + c0 + tc);
      tile[row][tc+0] = f2bf(v[0]);
      tile[row][tc+1] = f2bf(v[1]);
      tile[row][tc+2] = f2bf(v[2]);
      tile[row][tc+3] = f2bf(v[3]);
    }
    __syncthreads();
    #pragma unroll
    for (int rr = 0; rr < 4; ++rr) {
      int crow = tr + rr * 16;
      us4 o;
      #pragma unroll
      for (int i = 0; i < 4; ++i) o[i] = tile[tc + i][crow];
      *(us4*)(WvT + (long)(c0 + crow) * 1024 + j0 + tc) = o;
    }
  } else {                              // bias2 = Wo@bv + bo
    const int tb = b - 768;
    const int w = t >> 6, lane = t & 63;
    const int row = tb * 4 + w;
    float s = 0.f;
    #pragma unroll
    for (int c = 0; c < 4; ++c) {
      int col = c * 256 + lane * 4;
      float4v a = *(const float4v*)(Wo + (long)row * 1024 + col);
      float4v x = *(const float4v*)(bv + col);
      s += a[0]*x[0] + a[1]*x[1] + a[2]*x[2] + a[3]*x[3];
    }
    #pragma unroll
    for (int off = 32; off; off >>= 1) s += __shfl_down(s, off);
    if (lane == 0) bias2[row] = s + bo[row];
  }
}

// ---- fused: blocks 0..255 -> W = Wo@Wv (64x64 NT GEMM); 256..1279 -> V cvt
__global__ __launch_bounds__(512) void wgemm_vcvt(
    const unsigned short* __restrict__ Wob,
    const unsigned short* __restrict__ WvT,
    unsigned short* __restrict__ Wb,
    const float* __restrict__ V, unsigned short* __restrict__ Vb) {
  const int b = blockIdx.x;
  if (b < 256) {
    gemm_body<1024, 64, 64, 512, 2, 4, 1, 0, 0>(b, Wob, WvT, nullptr, Wb);
  } else {
    long off = ((long)(b - 256) * 512 + threadIdx.x) * 8;
    float4v a = *(const float4v*)(V + off);
    float4v c = *(const float4v*)(V + off + 4);
    ushort8 o;
    o[0]=f2bf(a[0]); o[1]=f2bf(a[1]); o[2]=f2bf(a[2]); o[3]=f2bf(a[3]);
    o[4]=f2bf(c[0]); o[5]=f2bf(c[1]); o[6]=f2bf(c[2]); o[7]=f2bf(c[3]);
    *(ushort8*)(Vb + off) = o;
  }
}

// ---- main: out = V@W^T + bias2, 128x128 tiles, 256 blocks, XCD swizzle
__global__ __launch_bounds__(512) void gemm_main(
    const unsigned short* __restrict__ A, const unsigned short* __restrict__ B,
    const float* __restrict__ bias, float* __restrict__ C) {
  gemm_body<4096, 128, 128, 512, 2, 4, 0, 1, 1>(blockIdx.x, A, B, bias, C);
}

extern "C" void kernel_launch(void* const* d_in, const int* in_sizes, int n_in,
                              void* d_out, int out_size, void* d_ws, size_t ws_size,
                              hipStream_t stream) {
  // dict order: 0:query 1:key 2:value 3:mask 4:Wq 5:bq 6:Wk 7:bk 8:Wv 9:bv 10:Wo 11:bo
  const float* value = (const float*)d_in[2];
  const float* Wv    = (const float*)d_in[8];
  const float* bv    = (const float*)d_in[9];
  const float* Wo    = (const float*)d_in[10];
  const float* bo    = (const float*)d_in[11];

  char* ws = (char*)d_ws;
  unsigned short* Vb    = (unsigned short*)(ws);              // 8 MiB
  unsigned short* Wob   = (unsigned short*)(ws + 8388608);    // 2 MiB
  unsigned short* WvTb  = (unsigned short*)(ws + 10485760);   // 2 MiB
  unsigned short* Wb    = (unsigned short*)(ws + 12582912);   // 2 MiB
  float*          bias2 = (float*)(ws + 14680064);            // 4 KiB
  float* out = (float*)d_out;

  prep_small<<<1024, 256, 0, stream>>>(Wv, Wo, bv, bo, Wob, WvTb, bias2);
  wgemm_vcvt<<<1280, 512, 0, stream>>>(Wob, WvTb, Wb, value, Vb);
  gemm_main<<<256, 512, 0, stream>>>(Vb, Wb, bias2, out);
}